// Round 2
// baseline (812.432 us; speedup 1.0000x reference)
//
#include <hip/hip_runtime.h>
#include <hip/hip_bf16.h>

// TemporalSpikeCoder latency encoding:
//   spike_times[b,f] = (int)((1 - x[b,f]) * 100)
//   out[b,t,f] = (spike_times[b,f] == t) ? 1.0f : 0.0f
// Shapes: x [B=2048, F=1024] f32, out [B, T=100, F] f32.
// Memory-bound on the 839 MB output write. Each thread owns 4 features of
// one batch row: loads x once as float4, writes 100 coalesced float4 stores.

constexpr int F  = 1024;   // features
constexpr int T  = 100;    // NUM_STEPS
constexpr int F4 = F / 4;  // float4s per feature row (256)

__global__ __launch_bounds__(F4) void TemporalSpikeCoder_78125455114738_kernel(
    const float* __restrict__ x, float* __restrict__ out) {
    const int b  = blockIdx.x;       // batch row (one block per row)
    const int f4 = threadIdx.x;      // float4 index within row, 0..255

    const float4 xv = reinterpret_cast<const float4*>(x)[(size_t)b * F4 + f4];
    // Match JAX: float32 math, truncation toward zero on int32 cast.
    const int st0 = (int)((1.0f - xv.x) * 100.0f);
    const int st1 = (int)((1.0f - xv.y) * 100.0f);
    const int st2 = (int)((1.0f - xv.z) * 100.0f);
    const int st3 = (int)((1.0f - xv.w) * 100.0f);

    float4* o = reinterpret_cast<float4*>(out) + (size_t)b * (T * F4) + f4;
    #pragma unroll 5
    for (int t = 0; t < T; ++t) {
        float4 v;
        v.x = (st0 == t) ? 1.0f : 0.0f;
        v.y = (st1 == t) ? 1.0f : 0.0f;
        v.z = (st2 == t) ? 1.0f : 0.0f;
        v.w = (st3 == t) ? 1.0f : 0.0f;
        o[(size_t)t * F4] = v;   // coalesced: 64 lanes x 16B = 1 KiB per wave
    }
}

extern "C" void kernel_launch(void* const* d_in, const int* in_sizes, int n_in,
                              void* d_out, int out_size, void* d_ws, size_t ws_size,
                              hipStream_t stream) {
    const float* x = (const float*)d_in[0];
    float* out = (float*)d_out;
    const int B = in_sizes[0] / F;   // 2048
    TemporalSpikeCoder_78125455114738_kernel<<<B, F4, 0, stream>>>(x, out);
}